// Round 6
// baseline (469.697 us; speedup 1.0000x reference)
//
#include <hip/hip_runtime.h>

// PLIF forward scan: v = beta*v + x_t; s = (v-1 >= 0); v *= (1-s)
// T=32 sequential in registers; B*N lanes fully parallel.
//
// R1: simple loop ~170us, 2.8 TB/s. R3: nt stores 205us. R4: C++ dbuf sank.
// R5: asm-load pipeline 170us. R6/R7: asm STORES -> garbage (source VGPRs
//     recycled while store in flight; loads-in-asm ok, stores never).
// R8: bit-pack + nt burst 193us: nt RAISED traffic 19% both ways. Dropped.
// R9: split pure-read scan + pure-write expand: k1+k2 ~= 177us (harness
//     model dur ~= 2*kernel+115, exact on R0/R4). Split was NEUTRAL =>
//     within-kernel read/write mixing is NOT the limiter. m13 linear copy
//     = 6.29 TB/s, fill = 6.4 TB/s, but every plane-strided kernel of ours
//     = ~3 TB/s per direction. Surviving theory: the 8MiB-stride plane
//     hopping itself halves DRAM efficiency for BOTH directions.
// R10 (this): linearize the WRITE stream (reads can't be linearized — the
//     scan dependency forces each thread to walk all 32 planes).
//     k1: unchanged scan; bit-words (8MiB) now go to d_ws (no more plane-0
//         aliasing), falls back to out-plane-0 if ws too small.
//     k2: inverted ownership — block (chunk x, plane y) sweeps a contiguous
//         128KB of out with coalesced block-linear stores; whole grid writes
//         the 268MB output in near-linear global order (fill-shaped). The
//         8MiB ws array is re-read once per plane from L2/L3 (HBM-free).
//     Clean A/B on the stride theory, write side only.

#define T_STEPS 32
#define CH 4
#define K2_ITERS 32
#define K2_SLOTS_PER_BLOCK (256 * K2_ITERS)   // 8192 float4-slots per block

typedef float    vfloat4 __attribute__((ext_vector_type(4)));
typedef unsigned vuint4  __attribute__((ext_vector_type(4)));

// Issue CH independent 16B loads into buf (volatile: pinned in program order).
#define ISSUE(buf, tc)                                                        \
    _Pragma("unroll")                                                         \
    for (int k = 0; k < CH; ++k) {                                            \
        unsigned voff = base16 + (unsigned)((tc) + k) * stride16;             \
        asm volatile("global_load_dwordx4 %0, %1, %2"                         \
                     : "=v"(buf[k])                                           \
                     : "v"(voff), "s"(xp));                                   \
    }

// Wait until only the N newest VMEM ops remain outstanding. Scan phase is
// loads-only, so counts are exact by construction. "memory" clobber keeps
// compiler-generated memory ops out of the counted region.
#define WAITN(n) asm volatile("s_waitcnt vmcnt(" #n ")" ::: "memory")

// Data-dependency fence: consumers must read the post-wait value (rule #18).
#define FENCE(buf)                                                            \
    _Pragma("unroll")                                                         \
    for (int k = 0; k < CH; ++k) asm volatile("" : "+v"(buf[k]));

// Scan one chunk: update v, record spike bits. NO stores in the scan phase.
#define SCAN(buf, tc)                                                         \
    _Pragma("unroll")                                                         \
    for (int k = 0; k < CH; ++k) {                                            \
        vfloat4 xt = buf[k];                                                  \
        _Pragma("unroll")                                                     \
        for (int c = 0; c < 4; ++c) {                                         \
            /* separate mul/add rounding: matches XLA non-contracted HLO */   \
            v[c] = __fadd_rn(__fmul_rn(beta, v[c]), xt[c]);                   \
            /* s = Heaviside(v - 1), reference op order */                    \
            float d  = __fadd_rn(v[c], -1.0f);                                \
            float sf = (d >= 0.0f) ? 1.0f : 0.0f;                             \
            sp[c] |= ((d >= 0.0f) ? 1u : 0u) << ((tc) + k);                   \
            /* hard reset, exact since sf in {0,1} */                         \
            v[c] *= (1.0f - sf);                                              \
        }                                                                     \
    }

// ---- k1: pure-read scan -> 8 MiB bit-packed output ----------------------
__global__ __launch_bounds__(256, 4) void plif_scan_kernel(
    const vfloat4* __restrict__ xp, const float* __restrict__ beta_raw,
    vuint4* __restrict__ bp, int bn4)
{
    int i = blockIdx.x * blockDim.x + threadIdx.x;
    if (i >= bn4) return;

    // beta = sigmoid(beta_raw); precise expf matches reference trajectory.
    float beta = 1.0f / (1.0f + expf(-beta_raw[0]));
    // Pin beta (and its uniform load + compiler wait) BEFORE the first ISSUE.
    asm volatile("" : "+v"(beta));

    unsigned base16   = (unsigned)i * 16u;        // byte offset of lane, <4GB
    unsigned stride16 = (unsigned)bn4 * 16u;      // byte stride per t-step

    vfloat4 v = (vfloat4)(0.0f, 0.0f, 0.0f, 0.0f);
    unsigned sp[4] = {0u, 0u, 0u, 0u};            // bit t of sp[c] = spike
    vfloat4 A[CH], B[CH];

    // Loads-only ladder: steady state keeps 8 x 16B loads in flight per lane.
    ISSUE(A, 0);
    ISSUE(B, 4);
    WAITN(4); FENCE(A); SCAN(A,  0); ISSUE(A,  8);
    WAITN(4); FENCE(B); SCAN(B,  4); ISSUE(B, 12);
    WAITN(4); FENCE(A); SCAN(A,  8); ISSUE(A, 16);
    WAITN(4); FENCE(B); SCAN(B, 12); ISSUE(B, 20);
    WAITN(4); FENCE(A); SCAN(A, 16); ISSUE(A, 24);
    WAITN(4); FENCE(B); SCAN(B, 20); ISSUE(B, 28);
    WAITN(4); FENCE(A); SCAN(A, 24);
    WAITN(0); FENCE(B); SCAN(B, 28);

    // 16B bit-packed result. Plain store (nt proven harmful, R3/R8);
    // compiler handles the store-source hazard (R6/R7 lesson).
    vuint4 bits; bits[0]=sp[0]; bits[1]=sp[1]; bits[2]=sp[2]; bits[3]=sp[3];
    bp[i] = bits;
}

// ---- k2 (primary): block-linear expansion, fill-shaped write stream -----
// Grid: (bn4 / 8192, 32). Block (x, y=t) owns out[t*bn4 + x*8192 .. +8192):
// 32 iterations of 256 coalesced float4 stores = contiguous 128KB sweep.
// ws bits: 1KB coalesced read per wave-iteration, L2/L3-hot (8MiB total).
__global__ __launch_bounds__(256, 4) void plif_expand_linear(
    const vuint4* __restrict__ wsbits, vfloat4* __restrict__ op, int bn4)
{
    int t = blockIdx.y;
    unsigned s0 = blockIdx.x * (unsigned)K2_SLOTS_PER_BLOCK + threadIdx.x;
    const vuint4* wp   = wsbits + s0;
    vfloat4*      outp = op + (size_t)t * (unsigned)bn4 + s0;

    _Pragma("unroll")
    for (int k = 0; k < K2_ITERS; ++k) {
        vuint4 u = wp[k * 256];
        vfloat4 s;
        _Pragma("unroll")
        for (int c = 0; c < 4; ++c)
            s[c] = ((u[c] >> t) & 1u) ? 1.0f : 0.0f;
        outp[k * 256] = s;
    }
}

// ---- k2 (fallback, no workspace): R9's per-thread plane-walk expand -----
__global__ __launch_bounds__(256, 4) void plif_expand_inplace(
    vfloat4* op, int bn4)
{
    int i = blockIdx.x * blockDim.x + threadIdx.x;
    if (i >= bn4) return;

    // Thread i is the SOLE reader and sole writer of out[i]: load bits, then
    // overwrite. asm tie + memory clobber: plane-0 store can't hoist above.
    vuint4 u = *((const vuint4*)op + i);
    asm volatile("" : "+v"(u) :: "memory");

    _Pragma("unroll")
    for (int t = 0; t < T_STEPS; ++t) {
        vfloat4 s;
        _Pragma("unroll")
        for (int c = 0; c < 4; ++c)
            s[c] = ((u[c] >> t) & 1u) ? 1.0f : 0.0f;
        op[i + t * bn4] = s;
    }
}

extern "C" void kernel_launch(void* const* d_in, const int* in_sizes, int n_in,
                              void* d_out, int out_size, void* d_ws, size_t ws_size,
                              hipStream_t stream) {
    const float* x        = (const float*)d_in[0];
    const float* beta_raw = (const float*)d_in[1];
    float* out            = (float*)d_out;

    int total = in_sizes[0];        // T*B*N = 67,108,864
    int bn    = total / T_STEPS;    // B*N   =  2,097,152
    int bn4   = bn / 4;             // float4 lanes = 524,288

    dim3 block(256);
    dim3 grid((bn4 + block.x - 1) / block.x);

    bool use_ws = (ws_size >= (size_t)bn4 * 16u) &&
                  (bn4 % K2_SLOTS_PER_BLOCK == 0);

    if (use_ws) {
        // k1 -> ws bits; k2 sweeps out linearly. Same stream => ordered,
        // kernel-boundary release makes ws visible across XCDs.
        plif_scan_kernel<<<grid, block, 0, stream>>>(
            (const vfloat4*)x, beta_raw, (vuint4*)d_ws, bn4);
        dim3 g2(bn4 / K2_SLOTS_PER_BLOCK, T_STEPS);
        plif_expand_linear<<<g2, block, 0, stream>>>(
            (const vuint4*)d_ws, (vfloat4*)out, bn4);
    } else {
        // Fallback: bits stashed in out plane 0 (R9 scheme).
        plif_scan_kernel<<<grid, block, 0, stream>>>(
            (const vfloat4*)x, beta_raw, (vuint4*)out, bn4);
        plif_expand_inplace<<<grid, block, 0, stream>>>(
            (vfloat4*)out, bn4);
    }
}

// Round 7
// 450.502 us; speedup vs baseline: 1.0426x; 1.0426x over previous
//
#include <hip/hip_runtime.h>

// PLIF forward scan: v = beta*v + x_t; s = (v-1 >= 0); v *= (1-s)
// T=32 sequential in registers; B*N lanes fully parallel.
//
// Journal:
// R1: simple loop, VGPR=28, (256,4): 170us, occupancy 48%.
// R3/R8: nt stores raise HBM traffic ~19% both directions. BANNED.
// R5: asm-load 8-deep pipeline, (256,4): 170us — identical to R1's 1-deep.
//     Per-wave ILP depth does NOTHING => in-flight depth per wave is clamped
//     by hw queue, not by software pipeline.
// R6/R7: inline-asm STORES -> garbage (source VGPRs recycled while store in
//     flight). Loads-in-asm ok; stores never.
// R9: direction-split (pure-read scan -> 8MB bits; pure-write expand):
//     k1+k2 ~ 184us. Split NEUTRAL => within-kernel r/w mixing not the
//     limiter.
// R10: block-linear write expand: neutral vs R9 (and possibly silently
//     fell back to R9 scheme — unverified ws_size; silent fallbacks are
//     ablation poison). Also moot: fillBuffer hits 6.5 TB/s with 1KB/wave
//     runs => write run-length was never a lever. Writes are posted.
// Invariant across R0/R5/R8/R9/R10: ~3.1 TB/s L2-side combined; copy ubench
//     6.3, fill 6.5. Every kernel so far ran at <=50% occupancy because of
//     __launch_bounds__(256,4) — the ONE untested first-order lever.
// R11 (this): occupancy experiment. READS are latency-chained (unlike
//     fill's posted writes): sustained read rate = outstanding-bytes /
//     latency. R5 proved per-wave depth doesn't add outstanding reads
//     (hw clamp); wave COUNT is the only remaining way. R1's simple loop
//     (~30 VGPR demand) + (256,8) => 64-VGPR cap, no spill risk, 32
//     waves/CU, grid 2048 = 8 blocks x 256 CUs exact.
//     Predict: occupancy >=90; if TLP-scalable, dur 170 -> 100-125us.
//     Falsifier: occ >=90 + dur ~170 => structural ~3.1 TB/s mixed ceiling
//     (three independent nulls: ILP depth, structure, TLP).

#define T_STEPS 32

typedef float vfloat4 __attribute__((ext_vector_type(4)));

__global__ __launch_bounds__(256, 8) void plif_fwd_kernel(
    const vfloat4* __restrict__ xp, const float* __restrict__ beta_raw,
    vfloat4* __restrict__ op, int bn4)
{
    int i = blockIdx.x * blockDim.x + threadIdx.x;
    if (i >= bn4) return;

    // beta = sigmoid(beta_raw); precise expf matches reference trajectory.
    float beta = 1.0f / (1.0f + expf(-beta_raw[0]));

    const vfloat4* rp = xp + i;
    vfloat4*       wp = op + i;

    vfloat4 v = (vfloat4)(0.0f, 0.0f, 0.0f, 0.0f);

    // Full unroll: 32 independent loads / 32 independent stores; the
    // compiler schedules lookahead within the 64-VGPR budget. No asm:
    // plain loads/stores are hazard-tracked (R6/R7 lesson), and R5 proved
    // hand pipelines buy nothing here. TLP (32 waves/CU) does the hiding.
    #pragma unroll
    for (int t = 0; t < T_STEPS; ++t) {
        vfloat4 xt = rp[(size_t)t * (unsigned)bn4];
        vfloat4 s;
        #pragma unroll
        for (int c = 0; c < 4; ++c) {
            /* separate mul/add rounding: matches XLA non-contracted HLO */
            v[c] = __fadd_rn(__fmul_rn(beta, v[c]), xt[c]);
            /* s = Heaviside(v - 1), reference op order */
            s[c] = (__fadd_rn(v[c], -1.0f) >= 0.0f) ? 1.0f : 0.0f;
            /* hard reset, exact since s in {0,1} */
            v[c] *= (1.0f - s[c]);
        }
        wp[(size_t)t * (unsigned)bn4] = s;
    }
}

extern "C" void kernel_launch(void* const* d_in, const int* in_sizes, int n_in,
                              void* d_out, int out_size, void* d_ws, size_t ws_size,
                              hipStream_t stream) {
    const float* x        = (const float*)d_in[0];
    const float* beta_raw = (const float*)d_in[1];
    float* out            = (float*)d_out;

    int total = in_sizes[0];        // T*B*N = 67,108,864
    int bn    = total / T_STEPS;    // B*N   =  2,097,152
    int bn4   = bn / 4;             // float4 lanes = 524,288

    dim3 block(256);
    dim3 grid((bn4 + block.x - 1) / block.x);   // 2048 = 8 blocks x 256 CUs
    plif_fwd_kernel<<<grid, block, 0, stream>>>(
        (const vfloat4*)x, beta_raw, (vfloat4*)out, bn4);
}